// Round 3
// baseline (8745.515 us; speedup 1.0000x reference)
//
#include <hip/hip_runtime.h>
#include <stdint.h>

// Problem constants
#define TT 256      // timesteps per phase
#define BB 256      // batch
#define II 128      // input dim
#define SS 256      // state dim
#define NTEAM 16    // row-group teams (16 rows each)
#define CGRP 16     // col blocks per team
#define RB 16       // batch rows per block
#define CB 16       // state cols per block
#define NSTEP (2*TT)
#define NBLK (NTEAM*CGRP)

typedef _Float16 h16;
typedef _Float16 half8 __attribute__((ext_vector_type(8)));
typedef float f32x4 __attribute__((ext_vector_type(4)));
typedef unsigned int u32x4 __attribute__((ext_vector_type(4)));

#define SBP 264     // s_buf padded row stride (halves)
#define XBP 136     // xbuf padded row stride (halves)

// ws layout (dwords):
#define XCHG_DW (NTEAM * 2 * RB * 128)     // 65536: [team][parity][16][128]
#define FLAG_DW (NTEAM * CGRP * 16)        // 4096: main flags, stride 16
#define PFLAG_DW (NTEAM * CGRP * 16)       // 4096: probe flags
#define VOTE_DW (NTEAM * CGRP)             // 256
#define XCDOF_DW NBLK                      // 256
#define BAR_DW 8
#define META_DW (FLAG_DW + PFLAG_DW + VOTE_DW + XCDOF_DW + BAR_DW)

__device__ __forceinline__ float sigmoidf_(float z) {
    return __builtin_amdgcn_rcpf(1.0f + __expf(-z));
}
__device__ __forceinline__ float tanhf_(float z) {
    return 1.0f - 2.0f * __builtin_amdgcn_rcpf(1.0f + __expf(2.0f * z));
}

// ---- L2-scope (same-XCD) primitives: sc0 = L1-bypass/write-through ----
__device__ __forceinline__ uint32_t ld_sc0(const uint32_t* p) {
    uint32_t v;
    asm volatile("global_load_dword %0, %1, off sc0\n\ts_waitcnt vmcnt(0)"
                 : "=&v"(v) : "v"(p) : "memory");
    return v;
}
__device__ __forceinline__ void st_sc0(uint32_t* p, uint32_t v) {
    asm volatile("global_store_dword %0, %1, off sc0" :: "v"(p), "v"(v) : "memory");
}
__device__ __forceinline__ void ld2x4_sc0(const uint32_t* p, u32x4& a, u32x4& b) {
    asm volatile("global_load_dwordx4 %0, %2, off sc0\n\t"
                 "global_load_dwordx4 %1, %2, off offset:16 sc0\n\t"
                 "s_waitcnt vmcnt(0)"
                 : "=&v"(a), "=&v"(b) : "v"(p) : "memory");
}
__device__ __forceinline__ void drain_vm() {
    asm volatile("s_waitcnt vmcnt(0)" ::: "memory");
}

// ---- agent-scope (cross-XCD, round-1-proven) primitives ----
__device__ __forceinline__ uint32_t ld_ag(const uint32_t* p) {
    return __hip_atomic_load(p, __ATOMIC_RELAXED, __HIP_MEMORY_SCOPE_AGENT);
}
__device__ __forceinline__ void st_ag(uint32_t* p, uint32_t v) {
    __hip_atomic_store(p, v, __ATOMIC_RELAXED, __HIP_MEMORY_SCOPE_AGENT);
}

struct Ptrs {
    const float *x;
    const float *Wi, *Ui, *Bi, *Wf, *Uf, *Bf, *Wo, *Uo, *Bo, *Wg, *Ug, *Bg;
    float* out;
    uint32_t* ws;
};

__global__ void lstm_zero_meta(uint32_t* meta, int n) {
    for (int i = threadIdx.x; i < n; i += blockDim.x) meta[i] = 0u;
}

__global__ __launch_bounds__(256) void lstm_persist(Ptrs p) {
    const int bid  = blockIdx.x;
    const int tid  = threadIdx.x;
    const int wave = tid >> 6;            // gate: 0=i 1=f 2=o 3=g
    const int lane = tid & 63;
    const int lrow = lane & 15;
    const int lk8  = (lane >> 4) * 8;
    const int erow = tid >> 4;
    const int ecol = tid & 15;

    __shared__ __align__(16) h16 s_buf[RB * SBP];
    __shared__ __align__(16) h16 xbuf[RB * XBP];
    __shared__ float zbuf[4][16][17];
    __shared__ float biasLds[4][16];
    __shared__ uint32_t xtab[NBLK];
    __shared__ uint32_t ok_sh[CGRP];
    __shared__ int pos_sh, fast_sh;
    // Force 1 block/CU (LDS total > 80KB) so XCDs fill 32 blocks each.
    __shared__ __align__(16) char lds_pad[64 * 1024];
    if (p.out == nullptr) lds_pad[tid] = 1;   // opaque keep-alive

    uint32_t* xchg   = p.ws;
    uint32_t* flags  = p.ws + XCHG_DW;
    uint32_t* pflag  = flags + FLAG_DW;
    uint32_t* vote   = pflag + PFLAG_DW;
    uint32_t* xcd_of = vote + VOTE_DW;
    uint32_t* bar    = xcd_of + XCDOF_DW;

    // ================= init: role discovery (deadlock-free) =================
    uint32_t xcd;
    asm volatile("s_getreg_b32 %0, hwreg(HW_REG_XCC_ID)" : "=s"(xcd));
    xcd &= 7;
    if (tid == 0) { st_ag(&xcd_of[bid], xcd); }
    drain_vm();
    // grid barrier #0
    __syncthreads();
    if (tid == 0) {
        __hip_atomic_fetch_add(&bar[0], 1u, __ATOMIC_ACQ_REL, __HIP_MEMORY_SCOPE_AGENT);
        while (__hip_atomic_load(&bar[0], __ATOMIC_ACQUIRE, __HIP_MEMORY_SCOPE_AGENT)
               < (uint32_t)NBLK)
            __builtin_amdgcn_s_sleep(2);
    }
    __syncthreads();
    // rank under (xcd, bid): bijection onto 0..255 regardless of placement
    if (tid < NBLK) xtab[tid] = ld_ag(&xcd_of[tid]);
    __syncthreads();
    if (tid == 0) {
        int ps = 0;
        for (int j = 0; j < NBLK; ++j) {
            uint32_t xj = xtab[j];
            if (xj < xcd || (xj == xcd && j < bid)) ++ps;
        }
        pos_sh = ps;
    }
    __syncthreads();
    const int pos  = pos_sh;
    const int team = pos >> 4;
    const int c    = pos & 15;
    const int r0   = team * RB;
    const int c0   = c * CB;

    uint32_t* teamx  = xchg + (size_t)team * (2 * RB * 128);
    uint32_t* teamfl = flags + (size_t)team * (CGRP * 16);
    uint32_t* teampf = pflag + (size_t)team * (CGRP * 16);

    // ================= coherence probe: can this team talk via L2? =========
    // Two rounds on the SAME line: round 2 catches the stale-L2 (cross-XCD)
    // case where round 1 passed via a cold fill.
    {
        bool ok = true;
        if (tid == 0) st_sc0(&teampf[c * 16], 1u);
        drain_vm();
        if (tid < CGRP) {
            const uint32_t* fp = &teampf[tid * 16];
            int it = 0;
            while (ld_sc0(fp) < 1u) {
                if (++it > 30000) { ok = false; break; }
                __builtin_amdgcn_s_sleep(1);
            }
        }
        __syncthreads();
        if (tid == 0) st_sc0(&teampf[c * 16], 2u);
        drain_vm();
        if (tid < CGRP) {
            const uint32_t* fp = &teampf[tid * 16];
            int it = 0;
            while (ok && ld_sc0(fp) < 2u) {
                if (++it > 30000) { ok = false; break; }
                __builtin_amdgcn_s_sleep(1);
            }
            ok_sh[tid] = ok ? 1u : 0u;
        }
        __syncthreads();
        if (tid == 0) {
            uint32_t a = 1;
            for (int j = 0; j < CGRP; ++j) a &= ok_sh[j];
            drain_vm();
            st_ag(&vote[team * CGRP + c], a ? 1u : 2u);
        }
        drain_vm();
        if (tid < CGRP) {
            uint32_t v;
            do {
                v = ld_ag(&vote[team * CGRP + tid]);
                if (!v) __builtin_amdgcn_s_sleep(2);
            } while (!v);
            ok_sh[tid] = (v == 1u) ? 1u : 0u;
        }
        __syncthreads();
        if (tid == 0) {
            uint32_t a = 1;
            for (int j = 0; j < CGRP; ++j) a &= ok_sh[j];
            fast_sh = (int)a;
        }
        __syncthreads();
    }
    const bool fastp = (fast_sh != 0);

    // ================= weights / state init =================
    const float* Uptr[4] = {p.Ui, p.Uf, p.Uo, p.Ug};
    const float* Wptr[4] = {p.Wi, p.Wf, p.Wo, p.Wg};
    const float* Bptr[4] = {p.Bi, p.Bf, p.Bo, p.Bg};

    if (tid < 64) biasLds[tid >> 4][tid & 15] = Bptr[tid >> 4][c0 + (tid & 15)];
    for (int idx = tid; idx < RB * SBP; idx += 256) s_buf[idx] = (h16)0.0f;

    const float* Ug = Uptr[wave];
    const float* Wg = Wptr[wave];
    half8 bU[8];
#pragma unroll
    for (int kc = 0; kc < 8; ++kc)
#pragma unroll
        for (int q = 0; q < 8; ++q)
            bU[kc][q] = (h16)Ug[(size_t)(kc * 32 + lk8 + q) * SS + c0 + lrow];
    half8 bW[4];
#pragma unroll
    for (int kc = 0; kc < 4; ++kc)
#pragma unroll
        for (int q = 0; q < 8; ++q)
            bW[kc][q] = (h16)Wg[(size_t)(kc * 32 + lk8 + q) * SS + c0 + lrow];

    float cst = 0.0f;

    // prefetch + stage x tile for t=0
    float4 pa, pb;
    {
        const float* xp = p.x + ((size_t)0 * BB + r0 + erow) * II + ecol * 8;
        pa = ((const float4*)xp)[0];
        pb = ((const float4*)xp)[1];
        half8 h;
        h[0]=(h16)pa.x; h[1]=(h16)pa.y; h[2]=(h16)pa.z; h[3]=(h16)pa.w;
        h[4]=(h16)pb.x; h[5]=(h16)pb.y; h[6]=(h16)pb.z; h[7]=(h16)pb.w;
        *(half8*)&xbuf[erow * XBP + ecol * 8] = h;
        const float* xp1 = p.x + ((size_t)1 * BB + r0 + erow) * II + ecol * 8;
        pa = ((const float4*)xp1)[0];
        pb = ((const float4*)xp1)[1];
    }
    __syncthreads();

    // ================= recurrence =================
    for (int n = 1; n <= NSTEP; ++n) {
        const bool enc = (n <= TT);

        f32x4 acc = {0.f, 0.f, 0.f, 0.f};
#pragma unroll
        for (int kc = 0; kc < 8; ++kc) {
            half8 a = *(const half8*)&s_buf[lrow * SBP + kc * 32 + lk8];
            acc = __builtin_amdgcn_mfma_f32_16x16x32_f16(a, bU[kc], acc, 0, 0, 0);
        }
        if (enc) {
#pragma unroll
            for (int kc = 0; kc < 4; ++kc) {
                half8 a = *(const half8*)&xbuf[lrow * XBP + kc * 32 + lk8];
                acc = __builtin_amdgcn_mfma_f32_16x16x32_f16(a, bW[kc], acc, 0, 0, 0);
            }
        }
#pragma unroll
        for (int q = 0; q < 4; ++q)
            zbuf[wave][(lane >> 4) * 4 + q][lrow] = acc[q];
        __syncthreads();

        float zi = zbuf[0][erow][ecol] + biasLds[0][ecol];
        float zf = zbuf[1][erow][ecol] + biasLds[1][ecol];
        float zo = zbuf[2][erow][ecol] + biasLds[2][ecol];
        float zg = zbuf[3][erow][ecol] + biasLds[3][ecol];
        float ig = sigmoidf_(zi);
        float fg = sigmoidf_(zf);
        float og = sigmoidf_(zo);
        float gg = tanhf_(zg);
        cst = cst * fg + gg * ig;
        float sv = tanhf_(cst) * og;

        if (!enc) {
            const int d = n - TT - 1;
            p.out[((size_t)d * BB + r0 + erow) * SS + c0 + ecol] = og;
        }

        if (n < NSTEP) {
            // ---- publish own s slice (fp16 pairs) ----
            float so = __shfl_xor(sv, 1);
            uint32_t pk = 0;
            if ((tid & 1) == 0) {
                uint16_t lo = __builtin_bit_cast(uint16_t, (h16)sv);
                uint16_t hi = __builtin_bit_cast(uint16_t, (h16)so);
                pk = (uint32_t)lo | ((uint32_t)hi << 16);
            }
            uint32_t* dst = teamx + (size_t)(n & 1) * (RB * 128)
                          + erow * 128 + c * 8 + (ecol >> 1);
            const uint32_t* src = teamx + (size_t)(n & 1) * (RB * 128)
                                + erow * 128 + ecol * 8;
            if (fastp) {
                if ((tid & 1) == 0) st_sc0(dst, pk);
                drain_vm();
                if (tid == 0) st_sc0(&teamfl[c * 16], (uint32_t)n);
                if (tid < CGRP) {
                    const uint32_t* fp = &teamfl[tid * 16];
                    while (ld_sc0(fp) < (uint32_t)n) { }
                }
                __syncthreads();
                u32x4 q0, q1;
                ld2x4_sc0(src, q0, q1);
                *(u32x4*)&s_buf[erow * SBP + ecol * 16]     = q0;
                *(u32x4*)&s_buf[erow * SBP + ecol * 16 + 8] = q1;
            } else {
                if ((tid & 1) == 0) st_ag(dst, pk);
                drain_vm();
                __syncthreads();
                if (tid == 0) st_ag(&teamfl[c * 16], (uint32_t)n);
                if (tid < CGRP) {
                    while (ld_ag(&teamfl[tid * 16]) < (uint32_t)n)
                        __builtin_amdgcn_s_sleep(1);
                }
                __syncthreads();
                uint32_t d0[8];
#pragma unroll
                for (int j = 0; j < 8; ++j) d0[j] = ld_ag(src + j);
                uint4* dst4 = (uint4*)&s_buf[erow * SBP + ecol * 16];
                dst4[0] = make_uint4(d0[0], d0[1], d0[2], d0[3]);
                dst4[1] = make_uint4(d0[4], d0[5], d0[6], d0[7]);
            }
            // ---- stage next x tile; prefetch one further ahead ----
            if (n < TT) {
                half8 h;
                h[0]=(h16)pa.x; h[1]=(h16)pa.y; h[2]=(h16)pa.z; h[3]=(h16)pa.w;
                h[4]=(h16)pb.x; h[5]=(h16)pb.y; h[6]=(h16)pb.z; h[7]=(h16)pb.w;
                *(half8*)&xbuf[erow * XBP + ecol * 8] = h;
                if (n + 1 < TT) {
                    const float* xp = p.x + ((size_t)(n + 1) * BB + r0 + erow) * II + ecol * 8;
                    pa = ((const float4*)xp)[0];
                    pb = ((const float4*)xp)[1];
                }
            }
            __syncthreads();
        }
    }
}

extern "C" void kernel_launch(void* const* d_in, const int* in_sizes, int n_in,
                              void* d_out, int out_size, void* d_ws, size_t ws_size,
                              hipStream_t stream) {
    Ptrs p;
    p.x  = (const float*)d_in[0];
    p.Wi = (const float*)d_in[1];  p.Ui = (const float*)d_in[2];  p.Bi = (const float*)d_in[3];
    p.Wf = (const float*)d_in[4];  p.Uf = (const float*)d_in[5];  p.Bf = (const float*)d_in[6];
    p.Wo = (const float*)d_in[7];  p.Uo = (const float*)d_in[8];  p.Bo = (const float*)d_in[9];
    p.Wg = (const float*)d_in[10]; p.Ug = (const float*)d_in[11]; p.Bg = (const float*)d_in[12];
    p.out = (float*)d_out;
    p.ws  = (uint32_t*)d_ws;

    uint32_t* meta = p.ws + XCHG_DW;
    hipLaunchKernelGGL(lstm_zero_meta, dim3(1), dim3(1024), 0, stream,
                       meta, META_DW);

    void* args[] = {&p};
    hipLaunchCooperativeKernel(lstm_persist, dim3(NBLK), dim3(256),
                               args, 0, stream);
}

// Round 5
// 2148.292 us; speedup vs baseline: 4.0709x; 4.0709x over previous
//
#include <hip/hip_runtime.h>
#include <stdint.h>

// Problem constants
#define TT 256      // timesteps per phase
#define BB 256      // batch
#define II 128      // input dim
#define SS 256      // state dim
#define NTEAM 16    // row teams (16 batch rows each)
#define CGRP 16     // col blocks per team
#define RB 16       // batch rows per block-chain
#define CB 16       // state cols per block
#define NSTEP (2*TT)
#define NBLK 128    // 8 team-pairs x 16 col-blocks; each block runs 2 chains

typedef _Float16 h16;
typedef _Float16 half8 __attribute__((ext_vector_type(8)));
typedef float f32x4 __attribute__((ext_vector_type(4)));

#define SBP 264     // s_buf padded row stride (halves)
#define XBP 136     // xbuf padded row stride (halves)

// ws layout (dwords):
#define XCHG_DW (NTEAM * 2 * RB * 128)   // 65536: [team][parity][16 rows][128]
#define FLAG_DW (NTEAM * 64)             // 1024: [team][c*4+wave]

__device__ __forceinline__ float sigmoidf_(float z) {
    return __builtin_amdgcn_rcpf(1.0f + __expf(-z));
}
__device__ __forceinline__ float tanhf_(float z) {
    return 1.0f - 2.0f * __builtin_amdgcn_rcpf(1.0f + __expf(2.0f * z));
}

// agent-scope (cross-XCD coherent point; round-1-proven) primitives
__device__ __forceinline__ uint32_t ld_ag(const uint32_t* p) {
    return __hip_atomic_load(p, __ATOMIC_RELAXED, __HIP_MEMORY_SCOPE_AGENT);
}
__device__ __forceinline__ void st_ag(uint32_t* p, uint32_t v) {
    __hip_atomic_store(p, v, __ATOMIC_RELAXED, __HIP_MEMORY_SCOPE_AGENT);
}
__device__ __forceinline__ void drain_vm() {
    asm volatile("s_waitcnt vmcnt(0)" ::: "memory");
}

struct Ptrs {
    const float *x;
    const float *Wi, *Ui, *Bi, *Wf, *Uf, *Bf, *Wo, *Uo, *Bo, *Wg, *Ug, *Bg;
    float* out;
    uint32_t* ws;
};

__global__ void lstm_zero_meta(uint32_t* meta, int n) {
    for (int i = threadIdx.x; i < n; i += blockDim.x) meta[i] = 0u;
}

__global__ __launch_bounds__(256, 1) void lstm_persist(Ptrs p) {
    const int bid  = blockIdx.x;
    const int tid  = threadIdx.x;
    const int wave = tid >> 6;            // gate: 0=i 1=f 2=o 3=g
    const int lane = tid & 63;
    const int lrow = lane & 15;           // A-row / B-col within tile
    const int lk8  = (lane >> 4) * 8;     // k sub-offset within 32-chunk
    const int erow = tid >> 4;            // elementwise (row,col) ownership
    const int ecol = tid & 15;

    const int tp  = bid >> 4;             // team pair 0..7
    const int c   = bid & 15;             // col role 0..15
    const int teamA = tp;                 // rows [teamA*16, +16)
    const int teamB = tp + 8;             // rows [teamB*16, +16)
    const int r0A = teamA * RB;
    const int r0B = teamB * RB;
    const int c0  = c * CB;

    __shared__ __align__(16) h16 s_bufA[RB * SBP];
    __shared__ __align__(16) h16 s_bufB[RB * SBP];
    __shared__ __align__(16) h16 xbufA[RB * XBP];
    __shared__ __align__(16) h16 xbufB[RB * XBP];
    __shared__ float zbufA[4][16][17];
    __shared__ float zbufB[4][16][17];
    __shared__ float biasLds[4][16];

    uint32_t* xchg  = p.ws;
    uint32_t* flags = p.ws + XCHG_DW;
    uint32_t* teamxA  = xchg + (size_t)teamA * (2 * RB * 128);
    uint32_t* teamxB  = xchg + (size_t)teamB * (2 * RB * 128);
    uint32_t* teamflA = flags + (size_t)teamA * 64;
    uint32_t* teamflB = flags + (size_t)teamB * 64;

    const float* Uptr[4] = {p.Ui, p.Uf, p.Uo, p.Ug};
    const float* Wptr[4] = {p.Wi, p.Wf, p.Wo, p.Wg};
    const float* Bptr[4] = {p.Bi, p.Bf, p.Bo, p.Bg};

    if (tid < 64) biasLds[tid >> 4][tid & 15] = Bptr[tid >> 4][c0 + (tid & 15)];
    for (int idx = tid; idx < RB * SBP; idx += 256) {
        s_bufA[idx] = (h16)0.0f;
        s_bufB[idx] = (h16)0.0f;
    }

    // Preload B-operand fragments (16x16x32: lane holds B[k=(lane>>4)*8+q][col=lane&15]).
    // Same columns for both chains -> one copy of U/W fragments.
    const float* Ug = Uptr[wave];
    const float* Wg = Wptr[wave];
    half8 bU[8];
#pragma unroll
    for (int kc = 0; kc < 8; ++kc)
#pragma unroll
        for (int q = 0; q < 8; ++q)
            bU[kc][q] = (h16)Ug[(size_t)(kc * 32 + lk8 + q) * SS + c0 + lrow];
    half8 bW[4];
#pragma unroll
    for (int kc = 0; kc < 4; ++kc)
#pragma unroll
        for (int q = 0; q < 8; ++q)
            bW[kc][q] = (h16)Wg[(size_t)(kc * 32 + lk8 + q) * SS + c0 + lrow];

    float cstA = 0.0f, cstB = 0.0f;

    // ---- stage x tiles for t=0; prefetch t=1 ----
    float4 paA, pbA, paB, pbB;
    {
        const float* xa = p.x + ((size_t)0 * BB + r0A + erow) * II + ecol * 8;
        const float* xb = p.x + ((size_t)0 * BB + r0B + erow) * II + ecol * 8;
        float4 a0 = ((const float4*)xa)[0], a1 = ((const float4*)xa)[1];
        float4 b0 = ((const float4*)xb)[0], b1 = ((const float4*)xb)[1];
        half8 ha, hb;
        ha[0]=(h16)a0.x; ha[1]=(h16)a0.y; ha[2]=(h16)a0.z; ha[3]=(h16)a0.w;
        ha[4]=(h16)a1.x; ha[5]=(h16)a1.y; ha[6]=(h16)a1.z; ha[7]=(h16)a1.w;
        hb[0]=(h16)b0.x; hb[1]=(h16)b0.y; hb[2]=(h16)b0.z; hb[3]=(h16)b0.w;
        hb[4]=(h16)b1.x; hb[5]=(h16)b1.y; hb[6]=(h16)b1.z; hb[7]=(h16)b1.w;
        *(half8*)&xbufA[erow * XBP + ecol * 8] = ha;
        *(half8*)&xbufB[erow * XBP + ecol * 8] = hb;
        const float* xa1 = p.x + ((size_t)1 * BB + r0A + erow) * II + ecol * 8;
        const float* xb1 = p.x + ((size_t)1 * BB + r0B + erow) * II + ecol * 8;
        paA = ((const float4*)xa1)[0]; pbA = ((const float4*)xa1)[1];
        paB = ((const float4*)xb1)[0]; pbB = ((const float4*)xb1)[1];
    }
    __syncthreads();

    for (int n = 1; n <= NSTEP; ++n) {
        const bool enc = (n <= TT);
        const int  par = n & 1;

        // ================= chain A: MFMA =================
        f32x4 accA = {0.f, 0.f, 0.f, 0.f};
#pragma unroll
        for (int kc = 0; kc < 8; ++kc) {
            half8 a = *(const half8*)&s_bufA[lrow * SBP + kc * 32 + lk8];
            accA = __builtin_amdgcn_mfma_f32_16x16x32_f16(a, bU[kc], accA, 0, 0, 0);
        }
        if (enc) {
#pragma unroll
            for (int kc = 0; kc < 4; ++kc) {
                half8 a = *(const half8*)&xbufA[lrow * XBP + kc * 32 + lk8];
                accA = __builtin_amdgcn_mfma_f32_16x16x32_f16(a, bW[kc], accA, 0, 0, 0);
            }
        }
#pragma unroll
        for (int q = 0; q < 4; ++q)
            zbufA[wave][(lane >> 4) * 4 + q][lrow] = accA[q];
        __syncthreads();   // B1: zbufA ready; s_bufA/xbufA reads done

        // ================= chain A: gates + publish =================
        {
            float zi = zbufA[0][erow][ecol] + biasLds[0][ecol];
            float zf = zbufA[1][erow][ecol] + biasLds[1][ecol];
            float zo = zbufA[2][erow][ecol] + biasLds[2][ecol];
            float zg = zbufA[3][erow][ecol] + biasLds[3][ecol];
            float ig = sigmoidf_(zi), fg = sigmoidf_(zf);
            float og = sigmoidf_(zo), gg = tanhf_(zg);
            cstA = cstA * fg + gg * ig;
            float sv = tanhf_(cstA) * og;
            if (!enc) {
                const int d = n - TT - 1;
                p.out[((size_t)d * BB + r0A + erow) * SS + c0 + ecol] = og;
            }
            h16 svh = (h16)sv;
            s_bufA[erow * SBP + c * 16 + ecol] = svh;   // own slice direct
            if (n < NSTEP) {
                float so = __shfl_xor(sv, 1);
                if ((tid & 1) == 0) {
                    uint16_t lo = __builtin_bit_cast(uint16_t, svh);
                    uint16_t hi = __builtin_bit_cast(uint16_t, (h16)so);
                    uint32_t pk = (uint32_t)lo | ((uint32_t)hi << 16);
                    st_ag(teamxA + (size_t)par * (RB * 128)
                          + erow * 128 + c * 8 + (ecol >> 1), pk);
                }
            }
        }

        // ================= chain B: MFMA (hides A's store commit) =========
        f32x4 accB = {0.f, 0.f, 0.f, 0.f};
#pragma unroll
        for (int kc = 0; kc < 8; ++kc) {
            half8 a = *(const half8*)&s_bufB[lrow * SBP + kc * 32 + lk8];
            accB = __builtin_amdgcn_mfma_f32_16x16x32_f16(a, bU[kc], accB, 0, 0, 0);
        }
        if (enc) {
#pragma unroll
            for (int kc = 0; kc < 4; ++kc) {
                half8 a = *(const half8*)&xbufB[lrow * XBP + kc * 32 + lk8];
                accB = __builtin_amdgcn_mfma_f32_16x16x32_f16(a, bW[kc], accB, 0, 0, 0);
            }
        }
#pragma unroll
        for (int q = 0; q < 4; ++q)
            zbufB[wave][(lane >> 4) * 4 + q][lrow] = accB[q];

        // flag A: per-wave drain (only THIS wave's stores) then per-wave flag
        if (n < NSTEP) {
            drain_vm();
            if (lane == 0) st_ag(&teamflA[c * 4 + wave], (uint32_t)n);
        }
        __syncthreads();   // B2: zbufB ready; s_bufB/xbufB reads done

        // ================= chain B: gates + publish =================
        {
            float zi = zbufB[0][erow][ecol] + biasLds[0][ecol];
            float zf = zbufB[1][erow][ecol] + biasLds[1][ecol];
            float zo = zbufB[2][erow][ecol] + biasLds[2][ecol];
            float zg = zbufB[3][erow][ecol] + biasLds[3][ecol];
            float ig = sigmoidf_(zi), fg = sigmoidf_(zf);
            float og = sigmoidf_(zo), gg = tanhf_(zg);
            cstB = cstB * fg + gg * ig;
            float sv = tanhf_(cstB) * og;
            if (!enc) {
                const int d = n - TT - 1;
                p.out[((size_t)d * BB + r0B + erow) * SS + c0 + ecol] = og;
            }
            h16 svh = (h16)sv;
            s_bufB[erow * SBP + c * 16 + ecol] = svh;
            if (n < NSTEP) {
                float so = __shfl_xor(sv, 1);
                if ((tid & 1) == 0) {
                    uint16_t lo = __builtin_bit_cast(uint16_t, svh);
                    uint16_t hi = __builtin_bit_cast(uint16_t, (h16)so);
                    uint32_t pk = (uint32_t)lo | ((uint32_t)hi << 16);
                    st_ag(teamxB + (size_t)par * (RB * 128)
                          + erow * 128 + c * 8 + (ecol >> 1), pk);
                }
                drain_vm();
                if (lane == 0) st_ag(&teamflB[c * 4 + wave], (uint32_t)n);
            }
        }

        if (n < NSTEP) {
            // ---- poll A (flags landed under B's compute), gather A ----
            while (ld_ag(&teamflA[lane]) < (uint32_t)n) { }
            const uint32_t* srcA = teamxA + (size_t)par * (RB * 128)
                                 + erow * 128 + ecol * 8;
            if (ecol != c) {
                uint32_t d0[8];
#pragma unroll
                for (int j = 0; j < 8; ++j) d0[j] = ld_ag(srcA + j);
                uint4* dst4 = (uint4*)&s_bufA[erow * SBP + ecol * 16];
                dst4[0] = make_uint4(d0[0], d0[1], d0[2], d0[3]);
                dst4[1] = make_uint4(d0[4], d0[5], d0[6], d0[7]);
            }
            // ---- poll B (landed under gather A), gather B ----
            while (ld_ag(&teamflB[lane]) < (uint32_t)n) { }
            const uint32_t* srcB = teamxB + (size_t)par * (RB * 128)
                                 + erow * 128 + ecol * 8;
            if (ecol != c) {
                uint32_t d0[8];
#pragma unroll
                for (int j = 0; j < 8; ++j) d0[j] = ld_ag(srcB + j);
                uint4* dst4 = (uint4*)&s_bufB[erow * SBP + ecol * 16];
                dst4[0] = make_uint4(d0[0], d0[1], d0[2], d0[3]);
                dst4[1] = make_uint4(d0[4], d0[5], d0[6], d0[7]);
            }
            // ---- stage next x tiles; prefetch one ahead ----
            if (n < TT) {
                half8 ha, hb;
                ha[0]=(h16)paA.x; ha[1]=(h16)paA.y; ha[2]=(h16)paA.z; ha[3]=(h16)paA.w;
                ha[4]=(h16)pbA.x; ha[5]=(h16)pbA.y; ha[6]=(h16)pbA.z; ha[7]=(h16)pbA.w;
                hb[0]=(h16)paB.x; hb[1]=(h16)paB.y; hb[2]=(h16)paB.z; hb[3]=(h16)paB.w;
                hb[4]=(h16)pbB.x; hb[5]=(h16)pbB.y; hb[6]=(h16)pbB.z; hb[7]=(h16)pbB.w;
                *(half8*)&xbufA[erow * XBP + ecol * 8] = ha;
                *(half8*)&xbufB[erow * XBP + ecol * 8] = hb;
                if (n + 1 < TT) {
                    const float* xa = p.x + ((size_t)(n + 1) * BB + r0A + erow) * II + ecol * 8;
                    const float* xb = p.x + ((size_t)(n + 1) * BB + r0B + erow) * II + ecol * 8;
                    paA = ((const float4*)xa)[0]; pbA = ((const float4*)xa)[1];
                    paB = ((const float4*)xb)[0]; pbB = ((const float4*)xb)[1];
                }
            }
            __syncthreads();   // B3: s_bufs/xbufs complete for step n+1
        }
    }
}

extern "C" void kernel_launch(void* const* d_in, const int* in_sizes, int n_in,
                              void* d_out, int out_size, void* d_ws, size_t ws_size,
                              hipStream_t stream) {
    Ptrs p;
    p.x  = (const float*)d_in[0];
    p.Wi = (const float*)d_in[1];  p.Ui = (const float*)d_in[2];  p.Bi = (const float*)d_in[3];
    p.Wf = (const float*)d_in[4];  p.Uf = (const float*)d_in[5];  p.Bf = (const float*)d_in[6];
    p.Wo = (const float*)d_in[7];  p.Uo = (const float*)d_in[8];  p.Bo = (const float*)d_in[9];
    p.Wg = (const float*)d_in[10]; p.Ug = (const float*)d_in[11]; p.Bg = (const float*)d_in[12];
    p.out = (float*)d_out;
    p.ws  = (uint32_t*)d_ws;

    uint32_t* meta = p.ws + XCHG_DW;
    hipLaunchKernelGGL(lstm_zero_meta, dim3(1), dim3(1024), 0, stream,
                       meta, FLAG_DW);

    void* args[] = {&p};
    hipLaunchCooperativeKernel(lstm_persist, dim3(NBLK), dim3(256),
                               args, 0, stream);
}